// Round 13
// baseline (25.899 us; speedup 1.0000x reference)
//
#include <hip/hip_runtime.h>
#include <hip/hip_bf16.h>

static constexpr int H = 512;
static constexpr int W = 512;
static constexpr int NIMG = 8;

// ws layout (bytes from d_ws):
//   F       @ 0        : [16][H][W] u16 = 8 MiB (axis-0 distance; 0xFFFF = empty column)
//   maxsq   @ 8Mi+0    : 16 f32  (task = dir*8+img; dir0 = max_{a} D_b^2, dir1 = max_{b} D_a^2)
//   anyflag @ 8Mi+64   : 16 int  (t<8: any(a_t), t>=8: any(b_{t-8}))
//   done    @ 8Mi+256  : 16 counters, each on its OWN 128B line (stride 32 ints)
//   gdone   @ 8Mi+2304 : 1 int (own line)
//   bm      @ 8Mi+4096 : [16][16][512] u32 = 512 KiB (bit r of bm[m][s][c] = mask m pixel (s*32+r, c))

__device__ __forceinline__ int edt_d(unsigned int m, int r, int row0, int ig,
                                     int carry_dn, int carry_up) {
    unsigned int below = m & (0xFFFFFFFFu >> (31 - r));   // bits 0..r
    int pos_dn = below ? (row0 + (31 - __clz((int)below))) : carry_dn;
    unsigned int above = m & (0xFFFFFFFFu << r);          // bits r..31
    int pos_up = above ? (row0 + (__ffs((int)above) - 1)) : carry_up;
    return min(ig - pos_dn, pos_up - ig);
}

// 512 threads: quad = tid&7 (4-col group, 32 cols/block), seg = tid>>3 (0..63, 8 rows each).
// 4 consecutive segs form a 32-row window; masks or-combined across sub-lanes via shfl_xor.
__global__ __launch_bounds__(512)
void k_col_edt(const float* __restrict__ A, const float* __restrict__ B,
               unsigned short* __restrict__ F, unsigned int* __restrict__ bm,
               float* __restrict__ maxsq, int* __restrict__ anyflag,
               int* __restrict__ done, int* __restrict__ gdone) {
    const int tid  = threadIdx.x;
    const int quad = tid & 7;
    const int seg  = tid >> 3;          // 0..63
    const int sub  = seg & 3;           // byte position within 32-row window
    const int win  = seg >> 2;          // 0..15 (32-row window)
    const int cg   = blockIdx.x;        // 0..15
    const int m16  = blockIdx.y;        // 0..15

    // fold k_init: only this block writes the slots; k_row_env (stream-ordered
    // after) is the only accumulator. ws is poisoned once + counters left full
    // by the previous replay, so re-init every call.
    if (cg == 0 && m16 == 0) {
        if (tid < 16)       { maxsq[tid] = 0.0f; anyflag[tid] = 0; }
        else if (tid < 32)  { done[(tid - 16) * 32] = 0; }   // 128B-strided counters
        else if (tid == 32) { *gdone = 0; }
    }

    const int colbase = cg * 32 + quad * 4;
    const float* src = (m16 < NIMG) ? (A + (size_t)m16 * H * W)
                                    : (B + (size_t)(m16 - NIMG) * H * W);
    unsigned short* f = F + (size_t)m16 * H * W;
    const int row0 = seg * 8;           // this thread's 8 rows
    const int w0   = win * 32;          // window start row

    // 8 independent float4 loads -> 4 column 8-bit masks
    unsigned int m0 = 0, m1 = 0, m2 = 0, m3 = 0;
    #pragma unroll
    for (int r = 0; r < 8; ++r) {
        float4 v = *reinterpret_cast<const float4*>(src + (size_t)(row0 + r) * W + colbase);
        m0 |= (v.x > 0.5f ? 1u : 0u) << r;
        m1 |= (v.y > 0.5f ? 1u : 0u) << r;
        m2 |= (v.z > 0.5f ? 1u : 0u) << r;
        m3 |= (v.w > 0.5f ? 1u : 0u) << r;
    }

    // assemble full 32-bit window masks: place own byte, or-combine across the
    // window's 4 sub-lanes (lane^8 -> seg^1, lane^16 -> seg^2; wave-internal)
    const int sh = 8 * sub;
    m0 <<= sh; m1 <<= sh; m2 <<= sh; m3 <<= sh;
    m0 |= __shfl_xor(m0, 8, 64);  m0 |= __shfl_xor(m0, 16, 64);
    m1 |= __shfl_xor(m1, 8, 64);  m1 |= __shfl_xor(m1, 16, 64);
    m2 |= __shfl_xor(m2, 8, 64);  m2 |= __shfl_xor(m2, 16, 64);
    m3 |= __shfl_xor(m3, 8, 64);  m3 |= __shfl_xor(m3, 16, 64);

    const int NEGS = -(1 << 21), POSS = (1 << 21);
    __shared__ int s_hi[16][32];
    __shared__ int s_lo[16][32];
    if (sub == 0) {
        int4 hi, lo;
        hi.x = m0 ? (w0 + 31 - __clz((int)m0)) : NEGS;
        hi.y = m1 ? (w0 + 31 - __clz((int)m1)) : NEGS;
        hi.z = m2 ? (w0 + 31 - __clz((int)m2)) : NEGS;
        hi.w = m3 ? (w0 + 31 - __clz((int)m3)) : NEGS;
        lo.x = m0 ? (w0 + __ffs((int)m0) - 1) : POSS;
        lo.y = m1 ? (w0 + __ffs((int)m1) - 1) : POSS;
        lo.z = m2 ? (w0 + __ffs((int)m2) - 1) : POSS;
        lo.w = m3 ? (w0 + __ffs((int)m3) - 1) : POSS;
        *reinterpret_cast<int4*>(&s_hi[win][quad * 4]) = hi;
        *reinterpret_cast<int4*>(&s_lo[win][quad * 4]) = lo;
        // persist bitmasks for k_row_env's membership test
        uint4 o = make_uint4(m0, m1, m2, m3);
        *reinterpret_cast<uint4*>(&bm[((size_t)m16 * 16 + win) * W + colbase]) = o;
    }
    __syncthreads();

    // cross-window carries (vectorized over the 4 owned columns)
    int4 cdn = {NEGS, NEGS, NEGS, NEGS};
    for (int t = 0; t < win; ++t) {
        int4 h = *reinterpret_cast<int4*>(&s_hi[t][quad * 4]);
        cdn.x = max(cdn.x, h.x); cdn.y = max(cdn.y, h.y);
        cdn.z = max(cdn.z, h.z); cdn.w = max(cdn.w, h.w);
    }
    int4 cup = {POSS, POSS, POSS, POSS};
    for (int t = win + 1; t < 16; ++t) {
        int4 l = *reinterpret_cast<int4*>(&s_lo[t][quad * 4]);
        cup.x = min(cup.x, l.x); cup.y = min(cup.y, l.y);
        cup.z = min(cup.z, l.z); cup.w = min(cup.w, l.w);
    }

    // per-row exact axis-0 distance for this thread's 8 rows, packed ushort4 stores
    #pragma unroll
    for (int k = 0; k < 8; ++k) {
        const int ig = row0 + k;        // global row
        const int rb = sh + k;          // bit index within window
        ushort4 o;
        o.x = (unsigned short)min(edt_d(m0, rb, w0, ig, cdn.x, cup.x), 65535);
        o.y = (unsigned short)min(edt_d(m1, rb, w0, ig, cdn.y, cup.y), 65535);
        o.z = (unsigned short)min(edt_d(m2, rb, w0, ig, cdn.z, cup.z), 65535);
        o.w = (unsigned short)min(edt_d(m3, rb, w0, ig, cdn.w, cup.w), 65535);
        *reinterpret_cast<ushort4*>(f + (size_t)ig * W + colbase) = o;
    }
}

// grid (16,16): block = (row-group rg, task). Each block: 32 rows (4 x 8-row
// iterations) of one task -> 4x fewer blocks than round 11 -> 4x smaller
// atomic tail (done queue 16/line, single scheduling round).
__global__ __launch_bounds__(512)
void k_row_env(const unsigned short* __restrict__ F, const unsigned int* __restrict__ bm,
               float* __restrict__ maxsq, int* __restrict__ anyflag,
               int* __restrict__ done, int* __restrict__ gdone,
               float* __restrict__ out) {
    const int task = blockIdx.y;            // 0..15
    const int rg   = blockIdx.x;            // 0..15 -> rows rg*32 .. rg*32+31
    const int img  = task & 7;
    const int dir  = task >> 3;             // 0: D_b at a-pixels ; 1: D_a at b-pixels
    const int wave = threadIdx.x >> 6;      // 0..7
    const int lane = threadIdx.x & 63;
    const int fsel = (dir == 0) ? (NIMG + img) : img;   // EDT source (the other mask)
    const int msel = (dir == 0) ? img : (NIMG + img);   // membership mask
    const int p0 = lane * 8;

    __shared__ float sf[8][512];            // fallback-only row buffer (wave-private)
    __shared__ float s_wmax[8];
    __shared__ int   s_wany[8];

    // membership bits: same bm words for all 32 rows of this block (row>>5 == rg)
    const unsigned int* brow = bm + ((size_t)msel * 16 + rg) * W + p0;
    uint4 b0 = *reinterpret_cast<const uint4*>(brow);
    uint4 b1 = *reinterpret_cast<const uint4*>(brow + 4);

    float vmax = 0.0f;
    int   vany = 0;

    #pragma unroll 1
    for (int it = 0; it < 4; ++it) {
        const int row = rg * 32 + it * 8 + wave;
        const unsigned short* frow = F + (size_t)fsel * H * W + (size_t)row * W;
        uint4 fu = *reinterpret_cast<const uint4*>(frow + p0);
        const int bit = it * 8 + wave;      // row & 31

        // w[8..15] = own f values; w[0..7] / w[16..23] = +-8 halo via lane shuffles
        float w[24];
        {
            unsigned int uu[4] = {fu.x, fu.y, fu.z, fu.w};
            #pragma unroll
            for (int e = 0; e < 4; ++e) {
                int dl = (int)(uu[e] & 0xFFFFu);
                int dh = (int)(uu[e] >> 16);
                w[8 + 2 * e]     = (dl == 65535) ? 1.0e12f : (float)(dl * dl);
                w[8 + 2 * e + 1] = (dh == 65535) ? 1.0e12f : (float)(dh * dh);
            }
        }
        #pragma unroll
        for (int e = 0; e < 8; ++e) {
            w[e]      = __shfl_up(w[8 + e], 1, 64);     // lane-1's elements = p0-8+e
            w[16 + e] = __shfl_down(w[8 + e], 1, 64);   // lane+1's elements = p0+8+e
        }
        if (lane == 0) {
            #pragma unroll
            for (int e = 0; e < 8; ++e) w[e] = 1.0e12f;
        }
        if (lane == 63) {
            #pragma unroll
            for (int e = 0; e < 8; ++e) w[16 + e] = 1.0e12f;
        }

        bool mk[8];
        mk[0] = (b0.x >> bit) & 1u; mk[1] = (b0.y >> bit) & 1u;
        mk[2] = (b0.z >> bit) & 1u; mk[3] = (b0.w >> bit) & 1u;
        mk[4] = (b1.x >> bit) & 1u; mk[5] = (b1.y >> bit) & 1u;
        mk[6] = (b1.z >> bit) & 1u; mk[7] = (b1.w >> bit) & 1u;
        #pragma unroll
        for (int p = 0; p < 8; ++p) vany |= (int)mk[p];

        // exact envelope, r<=8 fully in registers
        float best[8];
        #pragma unroll
        for (int p = 0; p < 8; ++p) best[p] = w[8 + p];
        #pragma unroll
        for (int r = 1; r <= 8; ++r) {
            const float rr = (float)(r * r);
            #pragma unroll
            for (int p = 0; p < 8; ++p)
                best[p] = fminf(best[p], fminf(rr + w[8 + p - r], rr + w[8 + p + r]));
        }

        // remaining candidates cost >= 81; rare exact fallback (wave-uniform
        // entry, wave-private LDS row filled lockstep -> no barrier needed)
        float bmax = 0.0f;
        #pragma unroll
        for (int p = 0; p < 8; ++p) bmax = fmaxf(bmax, mk[p] ? best[p] : 0.0f);
        if (!__all(bmax <= 81.0f)) {
            float* srow = &sf[wave][0];
            *reinterpret_cast<float4*>(srow + p0)     = make_float4(w[8],  w[9],  w[10], w[11]);
            *reinterpret_cast<float4*>(srow + p0 + 4) = make_float4(w[12], w[13], w[14], w[15]);
            for (int r = 9; r < W; ++r) {
                const float rr = (float)(r * r);
                if (__all(rr >= bmax)) break;
                #pragma unroll
                for (int p = 0; p < 8; ++p) {
                    int kl = p0 + p - r, kr = p0 + p + r;
                    float cl = (kl >= 0) ? srow[kl] : 1.0e12f;
                    float cr = (kr < W)  ? srow[kr] : 1.0e12f;
                    best[p] = fminf(best[p], fminf(rr + cl, rr + cr));
                }
                bmax = 0.0f;
                #pragma unroll
                for (int p = 0; p < 8; ++p) bmax = fmaxf(bmax, mk[p] ? best[p] : 0.0f);
            }
        }

        #pragma unroll
        for (int p = 0; p < 8; ++p) vmax = fmaxf(vmax, mk[p] ? best[p] : 0.0f);
    }

    // masked max: lane -> wave -> block -> one atomic per block
    #pragma unroll
    for (int off = 32; off > 0; off >>= 1)
        vmax = fmaxf(vmax, __shfl_down(vmax, off, 64));
    int wany = __any(vany) ? 1 : 0;
    if (lane == 0) { s_wmax[wave] = vmax; s_wany[wave] = wany; }
    __syncthreads();
    if (threadIdx.x == 0) {
        float mx = s_wmax[0]; int af = s_wany[0];
        #pragma unroll
        for (int q = 1; q < 8; ++q) { mx = fmaxf(mx, s_wmax[q]); af |= s_wany[q]; }
        // non-returning device-scope RMWs: fire-and-forget, no wave stall
        atomicMax((int*)&maxsq[task], __float_as_int(mx));   // values >= 0: int order == float order
        if (af) atomicOr(&anyflag[msel], 1);
        // order own atomics before the counter increment (ACK wait only; no fence)
        asm volatile("s_waitcnt vmcnt(0)" ::: "memory");
        // RETURNING atomics serialize per cache LINE; 16 increments/line now.
        int p = atomicAdd(&done[task * 32], 1);
        if (p == (int)gridDim.x - 1) {             // last block of this task
            int g = atomicAdd(gdone, 1);
            if (g == 15) {                         // last task overall
                float s = 0.0f;
                for (int i2 = 0; i2 < NIMG; ++i2) {
                    int af1 = __hip_atomic_load(&anyflag[i2],        __ATOMIC_RELAXED, __HIP_MEMORY_SCOPE_AGENT);
                    int af2 = __hip_atomic_load(&anyflag[NIMG + i2], __ATOMIC_RELAXED, __HIP_MEMORY_SCOPE_AGENT);
                    float m1 = __hip_atomic_load(&maxsq[i2],         __ATOMIC_RELAXED, __HIP_MEMORY_SCOPE_AGENT);
                    float m2 = __hip_atomic_load(&maxsq[NIMG + i2],  __ATOMIC_RELAXED, __HIP_MEMORY_SCOPE_AGENT);
                    float loss;
                    if (!af1 || !af2) {
                        loss = 1.0f;
                    } else {
                        float hd = sqrtf(fmaxf(m1, m2));
                        loss = 1.0f - 1.0f / (1.0f + hd);
                    }
                    s += loss;
                }
                out[0] = s * (1.0f / (float)NIMG);
            }
        }
    }
}

extern "C" void kernel_launch(void* const* d_in, const int* in_sizes, int n_in,
                              void* d_out, int out_size, void* d_ws, size_t ws_size,
                              hipStream_t stream) {
    const float* A = (const float*)d_in[0];
    const float* B = (const float*)d_in[1];
    char* base = (char*)d_ws;
    unsigned short* F = (unsigned short*)base;
    char* meta        = base + (size_t)16 * H * W * sizeof(unsigned short);
    float* maxsq      = (float*)(meta + 0);
    int*   anyflag    = (int*)(meta + 64);
    int*   done       = (int*)(meta + 256);    // 16 counters, 128B apart (2KB)
    int*   gdone      = (int*)(meta + 2304);   // own line
    unsigned int* bm  = (unsigned int*)(meta + 4096);
    float* out        = (float*)d_out;

    hipLaunchKernelGGL(k_col_edt, dim3(W / 32, 16), dim3(512), 0, stream,
                       A, B, F, bm, maxsq, anyflag, done, gdone);
    hipLaunchKernelGGL(k_row_env, dim3(16, 16), dim3(512), 0, stream,
                       F, bm, maxsq, anyflag, done, gdone, out);
}

// Round 14
// 21.887 us; speedup vs baseline: 1.1833x; 1.1833x over previous
//
#include <hip/hip_runtime.h>
#include <hip/hip_bf16.h>

static constexpr int H = 512;
static constexpr int W = 512;
static constexpr int NIMG = 8;

// ws layout (bytes from d_ws):
//   maxsq   @ 0      : 16 f32  (task = dir*8+img; dir0 = max_{a} D_b^2, dir1 = max_{b} D_a^2)
//   anyflag @ 64     : 16 int  (t<8: any(a_t), t>=8: any(b_{t-8}))
//   done    @ 256    : 16 counters, each on its OWN 128B line (stride 32 ints)
//   gdone   @ 2304   : 1 int (own line)
//   bm      @ 4096   : [16][16][512] u32 (bit r of bm[m][s][c] = mask m pixel (s*32+r, c))
//   cc      @ 4096+512Ki : [16][16][512] u32 (lo16 = cdn, hi16 = cup; i16, sentinels +-20000)
//
// No F array: k2 reconstructs axis-0 distances from bm+cc in registers.
// Sentinel exactness: sentinel-derived d^2 >= ~4.2e8 > 2*511^2 (max real candidate),
// so it is never selected unless the source mask is empty -> anyflag -> loss=1.

static constexpr int NEGS = -20000;
static constexpr int POSS =  20000;

// 512 threads: quad = tid&7 (4-col group, 32 cols/block), seg = tid>>3 (0..63, 8 rows each).
// 4 consecutive segs form a 32-row window; masks or-combined across sub-lanes via shfl_xor.
__global__ __launch_bounds__(512)
void k_col_edt(const float* __restrict__ A, const float* __restrict__ B,
               unsigned int* __restrict__ bm, unsigned int* __restrict__ cc,
               float* __restrict__ maxsq, int* __restrict__ anyflag,
               int* __restrict__ done, int* __restrict__ gdone) {
    const int tid  = threadIdx.x;
    const int quad = tid & 7;
    const int seg  = tid >> 3;          // 0..63
    const int sub  = seg & 3;           // byte position within 32-row window
    const int win  = seg >> 2;          // 0..15 (32-row window)
    const int cg   = blockIdx.x;        // 0..15
    const int m16  = blockIdx.y;        // 0..15

    // fold k_init: only this block writes the slots; k_row_env (stream-ordered
    // after) is the only accumulator. ws is poisoned once + counters left full
    // by the previous replay, so re-init every call.
    if (cg == 0 && m16 == 0) {
        if (tid < 16)       { maxsq[tid] = 0.0f; anyflag[tid] = 0; }
        else if (tid < 32)  { done[(tid - 16) * 32] = 0; }   // 128B-strided counters
        else if (tid == 32) { *gdone = 0; }
    }

    const int colbase = cg * 32 + quad * 4;
    const float* src = (m16 < NIMG) ? (A + (size_t)m16 * H * W)
                                    : (B + (size_t)(m16 - NIMG) * H * W);
    const int row0 = seg * 8;           // this thread's 8 rows
    const int w0   = win * 32;          // window start row

    // 8 independent float4 loads -> 4 column 8-bit masks
    unsigned int m0 = 0, m1 = 0, m2 = 0, m3 = 0;
    #pragma unroll
    for (int r = 0; r < 8; ++r) {
        float4 v = *reinterpret_cast<const float4*>(src + (size_t)(row0 + r) * W + colbase);
        m0 |= (v.x > 0.5f ? 1u : 0u) << r;
        m1 |= (v.y > 0.5f ? 1u : 0u) << r;
        m2 |= (v.z > 0.5f ? 1u : 0u) << r;
        m3 |= (v.w > 0.5f ? 1u : 0u) << r;
    }

    // assemble full 32-bit window masks: place own byte, or-combine across the
    // window's 4 sub-lanes (lane^8 -> seg^1, lane^16 -> seg^2; wave-internal)
    const int sh = 8 * sub;
    m0 <<= sh; m1 <<= sh; m2 <<= sh; m3 <<= sh;
    m0 |= __shfl_xor(m0, 8, 64);  m0 |= __shfl_xor(m0, 16, 64);
    m1 |= __shfl_xor(m1, 8, 64);  m1 |= __shfl_xor(m1, 16, 64);
    m2 |= __shfl_xor(m2, 8, 64);  m2 |= __shfl_xor(m2, 16, 64);
    m3 |= __shfl_xor(m3, 8, 64);  m3 |= __shfl_xor(m3, 16, 64);

    __shared__ int s_hi[16][32];
    __shared__ int s_lo[16][32];
    if (sub == 0) {
        int4 hi, lo;
        hi.x = m0 ? (w0 + 31 - __clz((int)m0)) : NEGS;
        hi.y = m1 ? (w0 + 31 - __clz((int)m1)) : NEGS;
        hi.z = m2 ? (w0 + 31 - __clz((int)m2)) : NEGS;
        hi.w = m3 ? (w0 + 31 - __clz((int)m3)) : NEGS;
        lo.x = m0 ? (w0 + __ffs((int)m0) - 1) : POSS;
        lo.y = m1 ? (w0 + __ffs((int)m1) - 1) : POSS;
        lo.z = m2 ? (w0 + __ffs((int)m2) - 1) : POSS;
        lo.w = m3 ? (w0 + __ffs((int)m3) - 1) : POSS;
        *reinterpret_cast<int4*>(&s_hi[win][quad * 4]) = hi;
        *reinterpret_cast<int4*>(&s_lo[win][quad * 4]) = lo;
        // persist bitmasks (k2 membership + EDT source)
        uint4 o = make_uint4(m0, m1, m2, m3);
        *reinterpret_cast<uint4*>(&bm[((size_t)m16 * 16 + win) * W + colbase]) = o;
    }
    __syncthreads();

    // cross-window carries for this window, packed i16 pairs -> cc (sub==0 only)
    if (sub == 0) {
        int4 cdn = {NEGS, NEGS, NEGS, NEGS};
        for (int t = 0; t < win; ++t) {
            int4 h = *reinterpret_cast<int4*>(&s_hi[t][quad * 4]);
            cdn.x = max(cdn.x, h.x); cdn.y = max(cdn.y, h.y);
            cdn.z = max(cdn.z, h.z); cdn.w = max(cdn.w, h.w);
        }
        int4 cup = {POSS, POSS, POSS, POSS};
        for (int t = win + 1; t < 16; ++t) {
            int4 l = *reinterpret_cast<int4*>(&s_lo[t][quad * 4]);
            cup.x = min(cup.x, l.x); cup.y = min(cup.y, l.y);
            cup.z = min(cup.z, l.z); cup.w = min(cup.w, l.w);
        }
        uint4 pk;
        pk.x = ((unsigned)cdn.x & 0xFFFFu) | ((unsigned)cup.x << 16);
        pk.y = ((unsigned)cdn.y & 0xFFFFu) | ((unsigned)cup.y << 16);
        pk.z = ((unsigned)cdn.z & 0xFFFFu) | ((unsigned)cup.z << 16);
        pk.w = ((unsigned)cdn.w & 0xFFFFu) | ((unsigned)cup.w << 16);
        *reinterpret_cast<uint4*>(&cc[((size_t)m16 * 16 + win) * W + colbase]) = pk;
    }
}

// grid (16,16): block = (row-group rg, task). Each block: 32 rows (4 x 8-row
// iterations) of one task; f-values reconstructed from bm+cc in registers.
__global__ __launch_bounds__(512)
void k_row_env(const unsigned int* __restrict__ bm, const unsigned int* __restrict__ cc,
               float* __restrict__ maxsq, int* __restrict__ anyflag,
               int* __restrict__ done, int* __restrict__ gdone,
               float* __restrict__ out) {
    const int task = blockIdx.y;            // 0..15
    const int rg   = blockIdx.x;            // 0..15 -> rows rg*32 .. rg*32+31
    const int img  = task & 7;
    const int dir  = task >> 3;             // 0: D_b at a-pixels ; 1: D_a at b-pixels
    const int wave = threadIdx.x >> 6;      // 0..7
    const int lane = threadIdx.x & 63;
    const int fsel = (dir == 0) ? (NIMG + img) : img;   // EDT source (the other mask)
    const int msel = (dir == 0) ? img : (NIMG + img);   // membership mask
    const int p0 = lane * 8;
    const int w0 = rg * 32;

    __shared__ float sf[8][512];            // fallback-only row buffer (wave-private)
    __shared__ float s_wmax[8];
    __shared__ int   s_wany[8];

    // all per-block state upfront (6 x dwordx4, independent, LLC-hot):
    const unsigned int* brow = bm + ((size_t)msel * 16 + rg) * W + p0;   // membership
    uint4 b0 = *reinterpret_cast<const uint4*>(brow);
    uint4 b1 = *reinterpret_cast<const uint4*>(brow + 4);
    const unsigned int* erow = bm + ((size_t)fsel * 16 + rg) * W + p0;   // EDT-source words
    uint4 e0 = *reinterpret_cast<const uint4*>(erow);
    uint4 e1 = *reinterpret_cast<const uint4*>(erow + 4);
    const unsigned int* crow = cc + ((size_t)fsel * 16 + rg) * W + p0;   // carries
    uint4 c0 = *reinterpret_cast<const uint4*>(crow);
    uint4 c1 = *reinterpret_cast<const uint4*>(crow + 4);

    unsigned int mw[8] = {e0.x, e0.y, e0.z, e0.w, e1.x, e1.y, e1.z, e1.w};
    unsigned int mb[8] = {b0.x, b0.y, b0.z, b0.w, b1.x, b1.y, b1.z, b1.w};
    int cd[8], cu[8];
    {
        unsigned int cwv[8] = {c0.x, c0.y, c0.z, c0.w, c1.x, c1.y, c1.z, c1.w};
        #pragma unroll
        for (int e = 0; e < 8; ++e) {
            cd[e] = (int)(short)(cwv[e] & 0xFFFFu);
            cu[e] = (int)(short)(cwv[e] >> 16);
        }
    }

    float vmax = 0.0f;
    int   vany = 0;

    #pragma unroll 1
    for (int it = 0; it < 4; ++it) {
        const int bit = it * 8 + wave;      // row index within window
        const int row = w0 + bit;

        // reconstruct f = d1^2 for own 8 columns from window word + carries
        float w[24];
        #pragma unroll
        for (int e = 0; e < 8; ++e) {
            unsigned int below = mw[e] & (0xFFFFFFFFu >> (31 - bit));
            int pos_dn = below ? (w0 + 31 - __clz((int)below)) : cd[e];
            unsigned int above = mw[e] & (0xFFFFFFFFu << bit);
            int pos_up = above ? (w0 + __ffs((int)above) - 1) : cu[e];
            int d = min(row - pos_dn, pos_up - row);   // real: <=511 (exact in f32)
            w[8 + e] = (float)(d * d);                 // sentinel: ~4.2e8, never selected
        }

        // +-8 halo via lane shuffles
        #pragma unroll
        for (int e = 0; e < 8; ++e) {
            w[e]      = __shfl_up(w[8 + e], 1, 64);     // lane-1's elements = p0-8+e
            w[16 + e] = __shfl_down(w[8 + e], 1, 64);   // lane+1's elements = p0+8+e
        }
        if (lane == 0) {
            #pragma unroll
            for (int e = 0; e < 8; ++e) w[e] = 1.0e12f;
        }
        if (lane == 63) {
            #pragma unroll
            for (int e = 0; e < 8; ++e) w[16 + e] = 1.0e12f;
        }

        bool mk[8];
        #pragma unroll
        for (int e = 0; e < 8; ++e) mk[e] = (mb[e] >> bit) & 1u;
        #pragma unroll
        for (int p = 0; p < 8; ++p) vany |= (int)mk[p];

        // exact envelope, r<=8 fully in registers
        float best[8];
        #pragma unroll
        for (int p = 0; p < 8; ++p) best[p] = w[8 + p];
        #pragma unroll
        for (int r = 1; r <= 8; ++r) {
            const float rr = (float)(r * r);
            #pragma unroll
            for (int p = 0; p < 8; ++p)
                best[p] = fminf(best[p], fminf(rr + w[8 + p - r], rr + w[8 + p + r]));
        }

        // remaining candidates cost >= 81; rare exact fallback (wave-uniform
        // entry, wave-private LDS row filled lockstep -> no barrier needed)
        float bmax = 0.0f;
        #pragma unroll
        for (int p = 0; p < 8; ++p) bmax = fmaxf(bmax, mk[p] ? best[p] : 0.0f);
        if (!__all(bmax <= 81.0f)) {
            float* srow = &sf[wave][0];
            *reinterpret_cast<float4*>(srow + p0)     = make_float4(w[8],  w[9],  w[10], w[11]);
            *reinterpret_cast<float4*>(srow + p0 + 4) = make_float4(w[12], w[13], w[14], w[15]);
            for (int r = 9; r < W; ++r) {
                const float rr = (float)(r * r);
                if (__all(rr >= bmax)) break;
                #pragma unroll
                for (int p = 0; p < 8; ++p) {
                    int kl = p0 + p - r, kr = p0 + p + r;
                    float cl = (kl >= 0) ? srow[kl] : 1.0e12f;
                    float cr = (kr < W)  ? srow[kr] : 1.0e12f;
                    best[p] = fminf(best[p], fminf(rr + cl, rr + cr));
                }
                bmax = 0.0f;
                #pragma unroll
                for (int p = 0; p < 8; ++p) bmax = fmaxf(bmax, mk[p] ? best[p] : 0.0f);
            }
        }

        #pragma unroll
        for (int p = 0; p < 8; ++p) vmax = fmaxf(vmax, mk[p] ? best[p] : 0.0f);
    }

    // masked max: lane -> wave -> block -> one atomic per block
    #pragma unroll
    for (int off = 32; off > 0; off >>= 1)
        vmax = fmaxf(vmax, __shfl_down(vmax, off, 64));
    int wany = __any(vany) ? 1 : 0;
    if (lane == 0) { s_wmax[wave] = vmax; s_wany[wave] = wany; }
    __syncthreads();
    if (threadIdx.x == 0) {
        float mx = s_wmax[0]; int af = s_wany[0];
        #pragma unroll
        for (int q = 1; q < 8; ++q) { mx = fmaxf(mx, s_wmax[q]); af |= s_wany[q]; }
        // non-returning device-scope RMWs: fire-and-forget, no wave stall
        atomicMax((int*)&maxsq[task], __float_as_int(mx));   // values >= 0: int order == float order
        if (af) atomicOr(&anyflag[msel], 1);
        // order own atomics before the counter increment (ACK wait only; no fence)
        asm volatile("s_waitcnt vmcnt(0)" ::: "memory");
        // RETURNING atomics serialize per cache LINE; 16 increments/line.
        int p = atomicAdd(&done[task * 32], 1);
        if (p == (int)gridDim.x - 1) {             // last block of this task
            int g = atomicAdd(gdone, 1);
            if (g == 15) {                         // last task overall
                float s = 0.0f;
                for (int i2 = 0; i2 < NIMG; ++i2) {
                    int af1 = __hip_atomic_load(&anyflag[i2],        __ATOMIC_RELAXED, __HIP_MEMORY_SCOPE_AGENT);
                    int af2 = __hip_atomic_load(&anyflag[NIMG + i2], __ATOMIC_RELAXED, __HIP_MEMORY_SCOPE_AGENT);
                    float m1 = __hip_atomic_load(&maxsq[i2],         __ATOMIC_RELAXED, __HIP_MEMORY_SCOPE_AGENT);
                    float m2 = __hip_atomic_load(&maxsq[NIMG + i2],  __ATOMIC_RELAXED, __HIP_MEMORY_SCOPE_AGENT);
                    float loss;
                    if (!af1 || !af2) {
                        loss = 1.0f;
                    } else {
                        float hd = sqrtf(fmaxf(m1, m2));
                        loss = 1.0f - 1.0f / (1.0f + hd);
                    }
                    s += loss;
                }
                out[0] = s * (1.0f / (float)NIMG);
            }
        }
    }
}

extern "C" void kernel_launch(void* const* d_in, const int* in_sizes, int n_in,
                              void* d_out, int out_size, void* d_ws, size_t ws_size,
                              hipStream_t stream) {
    const float* A = (const float*)d_in[0];
    const float* B = (const float*)d_in[1];
    char* base = (char*)d_ws;
    float* maxsq      = (float*)(base + 0);
    int*   anyflag    = (int*)(base + 64);
    int*   done       = (int*)(base + 256);    // 16 counters, 128B apart (2KB)
    int*   gdone      = (int*)(base + 2304);   // own line
    unsigned int* bm  = (unsigned int*)(base + 4096);
    unsigned int* cc  = (unsigned int*)(base + 4096 + 512 * 1024);
    float* out        = (float*)d_out;

    hipLaunchKernelGGL(k_col_edt, dim3(W / 32, 16), dim3(512), 0, stream,
                       A, B, bm, cc, maxsq, anyflag, done, gdone);
    hipLaunchKernelGGL(k_row_env, dim3(16, 16), dim3(512), 0, stream,
                       bm, cc, maxsq, anyflag, done, gdone, out);
}